// Round 1
// baseline (20999.174 us; speedup 1.0000x reference)
//
#include <hip/hip_runtime.h>
#include <math.h>

// GPT-2 small forward: B=2, T=1024, D=768, H=12, HD=64, L=12, V=50257
#define Bsz  2
#define Tlen 1024
#define Dm   768
#define Hh   12
#define HDm  64
#define Ll   12
#define Vv   50257

__device__ __forceinline__ float gelu_f(float x) {
  const float c = 0.7978845608028654f; // sqrt(2/pi)
  return 0.5f * x * (1.0f + tanhf(c * (x + 0.044715f * x * x * x)));
}

// ---------------- embedding: x = wte[idx] + wpe[t] ----------------
__global__ void embed_kernel(const int* __restrict__ idx, const float* __restrict__ wte,
                             const float* __restrict__ wpe, float* __restrict__ x) {
  int i = blockIdx.x * 256 + threadIdx.x;      // over B*T*D
  int d = i % Dm;
  int bt = i / Dm;
  int t = bt % Tlen;
  int tok = idx[bt];
  x[i] = wte[(size_t)tok * Dm + d] + wpe[(size_t)t * Dm + d];
}

// ---------------- layernorm (rows of length D=768), block=256 per row ----------------
__global__ __launch_bounds__(256) void ln_kernel(const float* __restrict__ x,
                                                 const float* __restrict__ w,
                                                 const float* __restrict__ b,
                                                 float* __restrict__ out) {
  __shared__ float sm[4], sm2[4];
  __shared__ float sMu, sRstd;
  int row = blockIdx.x;
  const float* xr = x + (size_t)row * Dm;
  float s = 0.f, s2 = 0.f;
  for (int i = threadIdx.x; i < Dm; i += 256) {
    float v = xr[i];
    s += v; s2 += v * v;
  }
  for (int o = 32; o > 0; o >>= 1) {
    s  += __shfl_down(s, o, 64);
    s2 += __shfl_down(s2, o, 64);
  }
  int lane = threadIdx.x & 63, wid = threadIdx.x >> 6;
  if (lane == 0) { sm[wid] = s; sm2[wid] = s2; }
  __syncthreads();
  if (threadIdx.x == 0) {
    float ts = sm[0] + sm[1] + sm[2] + sm[3];
    float ts2 = sm2[0] + sm2[1] + sm2[2] + sm2[3];
    float mu = ts / (float)Dm;
    float var = ts2 / (float)Dm - mu * mu;
    sMu = mu; sRstd = rsqrtf(var + 1e-5f);
  }
  __syncthreads();
  float mu = sMu, rstd = sRstd;
  float* yr = out + (size_t)row * Dm;
  for (int i = threadIdx.x; i < Dm; i += 256) {
    yr[i] = (xr[i] - mu) * rstd * w[i] + b[i];
  }
}

// ---------------- generic fp32 GEMM: C[M,N] = act(A[M,K]*B[K,N] + bias) + res ----------------
// BM=BN=64, BK=16; block 256 threads; each thread computes 4x4.
__global__ __launch_bounds__(256) void gemm_kernel(
    const float* __restrict__ A, const float* __restrict__ B,
    const float* __restrict__ bias, const float* __restrict__ res,
    float* __restrict__ C, int M, int N, int K, int act) {
  __shared__ float As[16][64];   // As[k][m]
  __shared__ float Bs[16][64];   // Bs[k][n]
  int tid = threadIdx.x;
  int rowBase = blockIdx.y * 64;
  int colBase = blockIdx.x * 64;
  int tx = tid & 15, ty = tid >> 4;
  float acc[4][4] = {};
  for (int k0 = 0; k0 < K; k0 += 16) {
#pragma unroll
    for (int i = 0; i < 4; ++i) {
      int idx = tid + i * 256;
      int r = idx >> 4, c = idx & 15;
      As[c][r] = A[(size_t)(rowBase + r) * K + k0 + c];
    }
#pragma unroll
    for (int i = 0; i < 4; ++i) {
      int idx = tid + i * 256;
      int r = idx >> 6, c = idx & 63;
      int col = colBase + c;
      Bs[r][c] = (col < N) ? B[(size_t)(k0 + r) * N + col] : 0.f;
    }
    __syncthreads();
#pragma unroll
    for (int k = 0; k < 16; ++k) {
      float a[4], bv[4];
#pragma unroll
      for (int i = 0; i < 4; ++i) a[i] = As[k][ty * 4 + i];
#pragma unroll
      for (int j = 0; j < 4; ++j) bv[j] = Bs[k][tx * 4 + j];
#pragma unroll
      for (int i = 0; i < 4; ++i)
#pragma unroll
        for (int j = 0; j < 4; ++j)
          acc[i][j] += a[i] * bv[j];
    }
    __syncthreads();
  }
#pragma unroll
  for (int i = 0; i < 4; ++i) {
    int row = rowBase + ty * 4 + i;
#pragma unroll
    for (int j = 0; j < 4; ++j) {
      int col = colBase + tx * 4 + j;
      if (col >= N) continue;
      float v = acc[i][j];
      if (bias) v += bias[col];
      if (act == 1) v = gelu_f(v);
      if (res) v += res[(size_t)row * N + col];
      C[(size_t)row * N + col] = v;
    }
  }
}

// ---------------- causal attention: one block (256 thr) per (b,h,q) row ----------------
// qkv layout [B,T,3*D]; q at offset h*64, k at 768+h*64, v at 1536+h*64.
__global__ __launch_bounds__(256) void attn_kernel(const float* __restrict__ qkv,
                                                   float* __restrict__ y) {
  int bid = blockIdx.x;
  int q = bid % Tlen;
  int rem = bid / Tlen;
  int h = rem % Hh;
  int b = rem / Hh;
  __shared__ float sc[Tlen];
  __shared__ float qv[HDm];
  __shared__ float red[4];
  __shared__ float part[4][HDm];
  const size_t rowStride = 3 * Dm;
  const float* qp = qkv + ((size_t)(b * Tlen + q)) * rowStride + h * HDm;
  if (threadIdx.x < HDm) qv[threadIdx.x] = qp[threadIdx.x];
  __syncthreads();
  const float scale = 0.125f; // 1/sqrt(64)
  float lmax = -INFINITY;
  for (int k = threadIdx.x; k < Tlen; k += 256) {
    float s;
    if (k <= q) {
      const float* kp = qkv + ((size_t)(b * Tlen + k)) * rowStride + Dm + h * HDm;
      float a = 0.f;
#pragma unroll 16
      for (int d = 0; d < HDm; ++d) a += qv[d] * kp[d];
      s = a * scale;
    } else {
      s = -INFINITY;
    }
    sc[k] = s;
    lmax = fmaxf(lmax, s);
  }
  for (int o = 32; o > 0; o >>= 1) lmax = fmaxf(lmax, __shfl_down(lmax, o, 64));
  int lane = threadIdx.x & 63, wid = threadIdx.x >> 6;
  if (lane == 0) red[wid] = lmax;
  __syncthreads();
  float m = fmaxf(fmaxf(red[0], red[1]), fmaxf(red[2], red[3]));
  __syncthreads();  // everyone has read red before reuse
  float lsum = 0.f;
  for (int k = threadIdx.x; k < Tlen; k += 256) {
    float p = expf(sc[k] - m);  // exp(-inf - m) = 0 for masked
    sc[k] = p;
    lsum += p;
  }
  for (int o = 32; o > 0; o >>= 1) lsum += __shfl_down(lsum, o, 64);
  if (lane == 0) red[wid] = lsum;
  __syncthreads();
  float inv = 1.0f / (red[0] + red[1] + red[2] + red[3]);
  // weighted sum over V: thread -> (d = tid&63, chunk = tid>>6)
  int d = threadIdx.x & 63;
  int pt = threadIdx.x >> 6;
  float acc = 0.f;
  int kbeg = pt * 256;
  int kend = min(kbeg + 256, q + 1);
  for (int k = kbeg; k < kend; ++k) {
    const float* vp = qkv + ((size_t)(b * Tlen + k)) * rowStride + 2 * Dm + h * HDm;
    acc += sc[k] * vp[d];
  }
  part[pt][d] = acc;
  __syncthreads();
  if (pt == 0) {
    float tot = (part[0][d] + part[1][d] + part[2][d] + part[3][d]) * inv;
    y[((size_t)(b * Tlen + q)) * Dm + h * HDm + d] = tot;
  }
}

extern "C" void kernel_launch(void* const* d_in, const int* in_sizes, int n_in,
                              void* d_out, int out_size, void* d_ws, size_t ws_size,
                              hipStream_t stream) {
  const int*   idx    = (const int*)d_in[0];
  const float* wte    = (const float*)d_in[1];
  const float* wpe    = (const float*)d_in[2];
  const float* ln1_w  = (const float*)d_in[3];
  const float* ln1_b  = (const float*)d_in[4];
  const float* attn_w = (const float*)d_in[5];
  const float* attn_b = (const float*)d_in[6];
  const float* proj_w = (const float*)d_in[7];
  const float* proj_b = (const float*)d_in[8];
  const float* ln2_w  = (const float*)d_in[9];
  const float* ln2_b  = (const float*)d_in[10];
  const float* fc_w   = (const float*)d_in[11];
  const float* fc_b   = (const float*)d_in[12];
  const float* fc2_w  = (const float*)d_in[13];
  const float* fc2_b  = (const float*)d_in[14];
  const float* lnf_w  = (const float*)d_in[15];
  const float* lnf_b  = (const float*)d_in[16];
  const float* lmw    = (const float*)d_in[17];
  float* out = (float*)d_out;

  const int M = Bsz * Tlen;  // 2048 rows
  float* x    = (float*)d_ws;                 // [M, D]
  float* hbuf = x + (size_t)M * Dm;           // [M, D]   (LN out / attn out)
  float* qkvb = hbuf + (size_t)M * Dm;        // [M, 3D]
  float* mbuf = qkvb + (size_t)M * 3 * Dm;    // [M, 4D]

  embed_kernel<<<(M * Dm) / 256, 256, 0, stream>>>(idx, wte, wpe, x);

  for (int l = 0; l < Ll; ++l) {
    // h = LN1(x)
    ln_kernel<<<M, 256, 0, stream>>>(x, ln1_w + l * Dm, ln1_b + l * Dm, hbuf);
    // qkv = h @ attn_w + attn_b
    {
      dim3 g((3 * Dm) / 64, M / 64);
      gemm_kernel<<<g, 256, 0, stream>>>(hbuf, attn_w + (size_t)l * Dm * 3 * Dm,
                                         attn_b + (size_t)l * 3 * Dm, nullptr,
                                         qkvb, M, 3 * Dm, Dm, 0);
    }
    // y = attention(qkv)   (into hbuf)
    attn_kernel<<<Bsz * Hh * Tlen, 256, 0, stream>>>(qkvb, hbuf);
    // x = x + y @ proj_w + proj_b
    {
      dim3 g(Dm / 64, M / 64);
      gemm_kernel<<<g, 256, 0, stream>>>(hbuf, proj_w + (size_t)l * Dm * Dm,
                                         proj_b + (size_t)l * Dm, x,
                                         x, M, Dm, Dm, 0);
    }
    // h = LN2(x)
    ln_kernel<<<M, 256, 0, stream>>>(x, ln2_w + l * Dm, ln2_b + l * Dm, hbuf);
    // m = gelu(h @ fc_w + fc_b)
    {
      dim3 g((4 * Dm) / 64, M / 64);
      gemm_kernel<<<g, 256, 0, stream>>>(hbuf, fc_w + (size_t)l * Dm * 4 * Dm,
                                         fc_b + (size_t)l * 4 * Dm, nullptr,
                                         mbuf, M, 4 * Dm, Dm, 1);
    }
    // x = x + m @ fc2_w + fc2_b
    {
      dim3 g(Dm / 64, M / 64);
      gemm_kernel<<<g, 256, 0, stream>>>(mbuf, fc2_w + (size_t)l * 4 * Dm * Dm,
                                         fc2_b + (size_t)l * Dm, x,
                                         x, M, Dm, 4 * Dm, 0);
    }
  }

  // final LN + lm_head
  ln_kernel<<<M, 256, 0, stream>>>(x, lnf_w, lnf_b, hbuf);
  {
    dim3 g((Vv + 63) / 64, M / 64);
    gemm_kernel<<<g, 256, 0, stream>>>(hbuf, lmw, nullptr, nullptr,
                                       out, M, Vv, Dm, 0);
  }
}

// Round 2
// 6237.806 us; speedup vs baseline: 3.3664x; 3.3664x over previous
//
#include <hip/hip_runtime.h>
#include <math.h>

// GPT-2 small forward: B=2, T=1024, D=768, H=12, HD=64, L=12, V=50257
#define Bsz  2
#define Tlen 1024
#define Dm   768
#define Hh   12
#define HDm  64
#define Ll   12
#define Vv   50257
#define Mrows (Bsz * Tlen)

typedef __attribute__((ext_vector_type(8))) short short8;
typedef __attribute__((ext_vector_type(4))) float f32x4;

__device__ __forceinline__ float bf2f(unsigned short u) {
  union { unsigned int i; float f; } v; v.i = ((unsigned int)u) << 16; return v.f;
}
__device__ __forceinline__ unsigned short f2bf(float f) {
  union { float f; unsigned int i; } v; v.f = f;
  unsigned int u = v.i;
  return (unsigned short)((u + 0x7FFFu + ((u >> 16) & 1u)) >> 16);  // RNE
}
__device__ __forceinline__ float gelu_f(float x) {
  const float c = 0.7978845608028654f; // sqrt(2/pi)
  return 0.5f * x * (1.0f + tanhf(c * (x + 0.044715f * x * x * x)));
}

// async global->LDS, 16B per lane. LDS dest must be wave-uniform base; HW adds lane*16.
__device__ __forceinline__ void gl_lds16(const unsigned short* g, unsigned short* l) {
  __builtin_amdgcn_global_load_lds(
      (const __attribute__((address_space(1))) unsigned int*)g,
      (__attribute__((address_space(3))) unsigned int*)l, 16, 0, 0);
}

// ---------------- embedding: x = wte[idx] + wpe[t] (fp32, float4) ----------------
__global__ void embed_kernel(const int* __restrict__ idx, const float* __restrict__ wte,
                             const float* __restrict__ wpe, float* __restrict__ x) {
  int i = (blockIdx.x * 256 + threadIdx.x) * 4;
  int d = i % Dm;
  int bt = i / Dm;
  int t = bt % Tlen;
  int tok = idx[bt];
  float4 a = *(const float4*)(wte + (size_t)tok * Dm + d);
  float4 p = *(const float4*)(wpe + (size_t)t * Dm + d);
  float4 r; r.x = a.x + p.x; r.y = a.y + p.y; r.z = a.z + p.z; r.w = a.w + p.w;
  *(float4*)(x + i) = r;
}

// ---------------- layernorm fp32 in -> bf16 out ----------------
__global__ __launch_bounds__(256) void ln_kernel(const float* __restrict__ x,
                                                 const float* __restrict__ w,
                                                 const float* __restrict__ b,
                                                 unsigned short* __restrict__ out) {
  __shared__ float sm[4], sm2[4];
  __shared__ float sMu, sRstd;
  int row = blockIdx.x;
  const float* xr = x + (size_t)row * Dm;
  float s = 0.f, s2 = 0.f;
  for (int i = threadIdx.x; i < Dm; i += 256) {
    float v = xr[i];
    s += v; s2 += v * v;
  }
  for (int o = 32; o > 0; o >>= 1) {
    s  += __shfl_down(s, o, 64);
    s2 += __shfl_down(s2, o, 64);
  }
  int lane = threadIdx.x & 63, wid = threadIdx.x >> 6;
  if (lane == 0) { sm[wid] = s; sm2[wid] = s2; }
  __syncthreads();
  if (threadIdx.x == 0) {
    float ts = sm[0] + sm[1] + sm[2] + sm[3];
    float ts2 = sm2[0] + sm2[1] + sm2[2] + sm2[3];
    float mu = ts / (float)Dm;
    float var = ts2 / (float)Dm - mu * mu;
    sMu = mu; sRstd = rsqrtf(var + 1e-5f);
  }
  __syncthreads();
  float mu = sMu, rstd = sRstd;
  unsigned short* yr = out + (size_t)row * Dm;
  for (int i = threadIdx.x; i < Dm; i += 256) {
    yr[i] = f2bf((xr[i] - mu) * rstd * w[i] + b[i]);
  }
}

// ---------------- transpose-convert: W[K][ldw] fp32 -> WT[n][K] bf16 ----------------
__global__ __launch_bounds__(256) void tconv_kernel(const float* __restrict__ W, int ldw,
                                                    int nValid, unsigned short* __restrict__ WT,
                                                    int K) {
  __shared__ float S[32][33];
  int n0 = blockIdx.x * 32, k0 = blockIdx.y * 32;
  int t = threadIdx.x;
  int nc = t & 31, kr0 = t >> 5;
#pragma unroll
  for (int i = 0; i < 4; ++i) {
    int kr = kr0 + i * 8;
    S[kr][nc] = (n0 + nc < nValid) ? W[(size_t)(k0 + kr) * ldw + n0 + nc] : 0.f;
  }
  __syncthreads();
  int r = t >> 3, c4 = (t & 7) * 4;
  ushort4 o;
  o.x = f2bf(S[c4 + 0][r]); o.y = f2bf(S[c4 + 1][r]);
  o.z = f2bf(S[c4 + 2][r]); o.w = f2bf(S[c4 + 3][r]);
  *(ushort4*)(WT + (size_t)(n0 + r) * K + k0 + c4) = o;
}

// ---------------- bf16 MFMA GEMM (m97 structure): C = act(A*B^T + bias) + res ----------------
// A [M][K] bf16, B [N][K] bf16 (pre-transposed weights). 128x128 tile, BK=32, 4 waves.
__global__ __launch_bounds__(256) void gemm_bf16(
    const unsigned short* __restrict__ A, const unsigned short* __restrict__ B, int K,
    const float* __restrict__ bias, const float* __restrict__ res,
    float* __restrict__ outF, unsigned short* __restrict__ outB,
    int ldc, int nValid, int act) {
  __shared__ alignas(16) unsigned short As[128][32];
  __shared__ alignas(16) unsigned short Bs[128][32];
  int tid = threadIdx.x;
  int rowBase = blockIdx.y * 128;
  int colBase = blockIdx.x * 128;
  int w = tid >> 6, l = tid & 63;
  int wr = w >> 1, wc = w & 1;

  // staging source: lane covers row tid/4 (+64 for issue 1), k-offset (tid%4)*8
  int srow = tid >> 2;
  int skk = (tid & 3) * 8;
  const unsigned short* aSrc = A + (size_t)(rowBase + srow) * K + skk;
  const unsigned short* bSrc = B + (size_t)(colBase + srow) * K + skk;
  unsigned short* aL0 = &As[w * 16][0];
  unsigned short* aL1 = &As[w * 16 + 64][0];
  unsigned short* bL0 = &Bs[w * 16][0];
  unsigned short* bL1 = &Bs[w * 16 + 64][0];

  f32x4 acc[4][4];
#pragma unroll
  for (int m = 0; m < 4; ++m)
#pragma unroll
    for (int n = 0; n < 4; ++n) acc[m][n] = (f32x4){0.f, 0.f, 0.f, 0.f};

  int fr = l & 15, fq = l >> 4;

  for (int k0 = 0; k0 < K; k0 += 32) {
    gl_lds16(aSrc + k0, aL0);
    gl_lds16(aSrc + (size_t)64 * K + k0, aL1);
    gl_lds16(bSrc + k0, bL0);
    gl_lds16(bSrc + (size_t)64 * K + k0, bL1);
    asm volatile("s_waitcnt vmcnt(0)" ::: "memory");
    __syncthreads();

    short8 af[4], bfr[4];
#pragma unroll
    for (int m = 0; m < 4; ++m)
      af[m] = *(const short8*)&As[wr * 64 + m * 16 + fr][fq * 8];
#pragma unroll
    for (int n = 0; n < 4; ++n)
      bfr[n] = *(const short8*)&Bs[wc * 64 + n * 16 + fr][fq * 8];
#pragma unroll
    for (int m = 0; m < 4; ++m)
#pragma unroll
      for (int n = 0; n < 4; ++n)
        acc[m][n] = __builtin_amdgcn_mfma_f32_16x16x32_bf16(af[m], bfr[n], acc[m][n], 0, 0, 0);
    __syncthreads();
  }

  // epilogue: C/D layout col=lane&15, row=(lane>>4)*4+reg
#pragma unroll
  for (int m = 0; m < 4; ++m) {
    int row = rowBase + wr * 64 + m * 16 + fq * 4;
#pragma unroll
    for (int n = 0; n < 4; ++n) {
      int col = colBase + wc * 64 + n * 16 + fr;
      if (col >= nValid) continue;
      float bv = bias ? bias[col] : 0.f;
#pragma unroll
      for (int j = 0; j < 4; ++j) {
        float v = acc[m][n][j] + bv;
        if (act) v = gelu_f(v);
        if (res) v += res[(size_t)(row + j) * ldc + col];
        if (outF) outF[(size_t)(row + j) * ldc + col] = v;
        else      outB[(size_t)(row + j) * ldc + col] = f2bf(v);
      }
    }
  }
}

// ---------------- flash-style SIMT attention, bf16 qkv in, bf16 y out ----------------
// block = 256 threads handles one (b,h) x 32-query tile; k-tiles of 32 with online softmax.
__global__ __launch_bounds__(256) void attn_kernel(const unsigned short* __restrict__ qkv,
                                                   unsigned short* __restrict__ y) {
  int bx = blockIdx.x;
  int qt = bx & 31;              // T/32 = 32
  int h = (bx >> 5) % Hh;
  int b = bx / (32 * Hh);
  int t = threadIdx.x;
  __shared__ float Qs[32][65], Ks[32][65], Vs[32][65];
  __shared__ float Ss[32][33];
  int q0 = qt * 32;
  int lr = t >> 3;               // load row 0..31
  int lc = (t & 7) * 8;          // load col 0..56

  {  // Q tile (scale folded in)
    const unsigned short* src = qkv + ((size_t)(b * Tlen + q0 + lr)) * (3 * Dm) + h * HDm + lc;
    uint4 u = *(const uint4*)src;
    unsigned int uu[4] = {u.x, u.y, u.z, u.w};
#pragma unroll
    for (int j = 0; j < 4; ++j) {
      Qs[lr][lc + 2 * j]     = bf2f((unsigned short)(uu[j] & 0xFFFFu)) * 0.125f;
      Qs[lr][lc + 2 * j + 1] = bf2f((unsigned short)(uu[j] >> 16)) * 0.125f;
    }
  }

  int q_own = t & 31, dgrp = t >> 5, db = dgrp * 8;
  int q_glob = q0 + q_own;
  float o[8] = {0.f, 0.f, 0.f, 0.f, 0.f, 0.f, 0.f, 0.f};
  float m_run = -1e30f, l_run = 0.f;

  for (int kt = 0; kt <= qt; ++kt) {
    int kbase = kt * 32;
    {  // stage K, V tiles
      size_t rowoff = ((size_t)(b * Tlen + kbase + lr)) * (3 * Dm) + h * HDm + lc;
      uint4 uk = *(const uint4*)(qkv + rowoff + Dm);
      uint4 uv = *(const uint4*)(qkv + rowoff + 2 * Dm);
      unsigned int kk[4] = {uk.x, uk.y, uk.z, uk.w};
      unsigned int vv[4] = {uv.x, uv.y, uv.z, uv.w};
#pragma unroll
      for (int j = 0; j < 4; ++j) {
        Ks[lr][lc + 2 * j]     = bf2f((unsigned short)(kk[j] & 0xFFFFu));
        Ks[lr][lc + 2 * j + 1] = bf2f((unsigned short)(kk[j] >> 16));
        Vs[lr][lc + 2 * j]     = bf2f((unsigned short)(vv[j] & 0xFFFFu));
        Vs[lr][lc + 2 * j + 1] = bf2f((unsigned short)(vv[j] >> 16));
      }
    }
    __syncthreads();

    // scores: thread computes 4 columns kc = dgrp*4 + jj for row q_own
    float sv[4] = {0.f, 0.f, 0.f, 0.f};
#pragma unroll
    for (int d = 0; d < 64; ++d) {
      float qv = Qs[q_own][d];
#pragma unroll
      for (int jj = 0; jj < 4; ++jj) sv[jj] += qv * Ks[dgrp * 4 + jj][d];
    }
#pragma unroll
    for (int jj = 0; jj < 4; ++jj) {
      int kc = dgrp * 4 + jj;
      Ss[q_own][kc] = (kbase + kc <= q_glob) ? sv[jj] : -1e30f;
    }
    __syncthreads();

    // online softmax + PV
    float tmax = -1e30f;
#pragma unroll
    for (int c = 0; c < 32; ++c) tmax = fmaxf(tmax, Ss[q_own][c]);
    float m_new = fmaxf(m_run, tmax);
    float corr = __expf(m_run - m_new);
    float lsum = l_run * corr;
#pragma unroll
    for (int dd = 0; dd < 8; ++dd) o[dd] *= corr;
    for (int c = 0; c < 32; ++c) {
      float p = __expf(Ss[q_own][c] - m_new);
      lsum += p;
#pragma unroll
      for (int dd = 0; dd < 8; ++dd) o[dd] += p * Vs[c][db + dd];
    }
    m_run = m_new; l_run = lsum;
    __syncthreads();
  }

  float inv = 1.f / l_run;
  unsigned int pk[4];
#pragma unroll
  for (int j = 0; j < 4; ++j) {
    unsigned short lo = f2bf(o[2 * j] * inv);
    unsigned short hi = f2bf(o[2 * j + 1] * inv);
    pk[j] = (unsigned int)lo | ((unsigned int)hi << 16);
  }
  uint4 u; u.x = pk[0]; u.y = pk[1]; u.z = pk[2]; u.w = pk[3];
  *(uint4*)(y + ((size_t)(b * Tlen + q_glob)) * Dm + h * HDm + db) = u;
}

extern "C" void kernel_launch(void* const* d_in, const int* in_sizes, int n_in,
                              void* d_out, int out_size, void* d_ws, size_t ws_size,
                              hipStream_t stream) {
  const int*   idx    = (const int*)d_in[0];
  const float* wte    = (const float*)d_in[1];
  const float* wpe    = (const float*)d_in[2];
  const float* ln1_w  = (const float*)d_in[3];
  const float* ln1_b  = (const float*)d_in[4];
  const float* attn_w = (const float*)d_in[5];
  const float* attn_b = (const float*)d_in[6];
  const float* proj_w = (const float*)d_in[7];
  const float* proj_b = (const float*)d_in[8];
  const float* ln2_w  = (const float*)d_in[9];
  const float* ln2_b  = (const float*)d_in[10];
  const float* fc_w   = (const float*)d_in[11];
  const float* fc_b   = (const float*)d_in[12];
  const float* fc2_w  = (const float*)d_in[13];
  const float* fc2_b  = (const float*)d_in[14];
  const float* lnf_w  = (const float*)d_in[15];
  const float* lnf_b  = (const float*)d_in[16];
  const float* lmw    = (const float*)d_in[17];
  float* out = (float*)d_out;

  // workspace layout (46.6 MB total; round-1 used 63 MB successfully)
  float* x = (float*)d_ws;                                    // [M][768] fp32
  unsigned short* qkvb = (unsigned short*)(x + (size_t)Mrows * Dm);   // [M][2304] bf16
  unsigned short* xb   = qkvb + (size_t)Mrows * 3 * Dm;       // [M][768] bf16
  unsigned short* yb   = xb + (size_t)Mrows * Dm;             // [M][768] bf16
  unsigned short* mb   = yb + (size_t)Mrows * Dm;             // [M][3072] bf16
  unsigned short* wbuf = mb + (size_t)Mrows * 4 * Dm;         // per-layer W^T bf16
  unsigned short* wAttn = wbuf;                               // [2304][768]
  unsigned short* wProj = wAttn + (size_t)3 * Dm * Dm;        // [768][768]
  unsigned short* wFc   = wProj + (size_t)Dm * Dm;            // [3072][768]
  unsigned short* wFc2  = wFc + (size_t)4 * Dm * Dm;          // [768][3072]

  embed_kernel<<<(Mrows * Dm) / 1024, 256, 0, stream>>>(idx, wte, wpe, x);

  for (int l = 0; l < Ll; ++l) {
    // convert this layer's weights to transposed bf16
    tconv_kernel<<<dim3(72, 24), 256, 0, stream>>>(attn_w + (size_t)l * Dm * 3 * Dm, 3 * Dm, 3 * Dm, wAttn, Dm);
    tconv_kernel<<<dim3(24, 24), 256, 0, stream>>>(proj_w + (size_t)l * Dm * Dm, Dm, Dm, wProj, Dm);
    tconv_kernel<<<dim3(96, 24), 256, 0, stream>>>(fc_w + (size_t)l * Dm * 4 * Dm, 4 * Dm, 4 * Dm, wFc, Dm);
    tconv_kernel<<<dim3(24, 96), 256, 0, stream>>>(fc2_w + (size_t)l * 4 * Dm * Dm, Dm, Dm, wFc2, 4 * Dm);

    ln_kernel<<<Mrows, 256, 0, stream>>>(x, ln1_w + l * Dm, ln1_b + l * Dm, xb);
    gemm_bf16<<<dim3(18, 16), 256, 0, stream>>>(xb, wAttn, Dm, attn_b + (size_t)l * 3 * Dm,
                                                nullptr, nullptr, qkvb, 3 * Dm, 3 * Dm, 0);
    attn_kernel<<<Bsz * Hh * 32, 256, 0, stream>>>(qkvb, yb);
    gemm_bf16<<<dim3(6, 16), 256, 0, stream>>>(yb, wProj, Dm, proj_b + (size_t)l * Dm,
                                               x, x, nullptr, Dm, Dm, 0);
    ln_kernel<<<Mrows, 256, 0, stream>>>(x, ln2_w + l * Dm, ln2_b + l * Dm, xb);
    gemm_bf16<<<dim3(24, 16), 256, 0, stream>>>(xb, wFc, Dm, fc_b + (size_t)l * 4 * Dm,
                                                nullptr, nullptr, mb, 4 * Dm, 4 * Dm, 1);
    gemm_bf16<<<dim3(6, 16), 256, 0, stream>>>(mb, wFc2, 4 * Dm, fc2_b + (size_t)l * Dm,
                                               x, x, nullptr, Dm, Dm, 0);
  }

  // final LN + chunked lm_head
  ln_kernel<<<Mrows, 256, 0, stream>>>(x, lnf_w, lnf_b, xb);
  for (int base = 0; base < Vv; base += 8192) {
    int ncv = Vv - base; if (ncv > 8192) ncv = 8192;
    int ntiles = (ncv + 127) / 128;
    tconv_kernel<<<dim3(ntiles * 4, 24), 256, 0, stream>>>(lmw + base, Vv, ncv, wbuf, Dm);
    gemm_bf16<<<dim3(ntiles, 16), 256, 0, stream>>>(xb, wbuf, Dm, nullptr, nullptr,
                                                    out + base, nullptr, Vv, ncv, 0);
  }
}

// Round 3
// 3643.089 us; speedup vs baseline: 5.7641x; 1.7122x over previous
//
#include <hip/hip_runtime.h>
#include <math.h>

// GPT-2 small forward: B=2, T=1024, D=768, H=12, HD=64, L=12, V=50257
#define Bsz  2
#define Tlen 1024
#define Dm   768
#define Hh   12
#define HDm  64
#define Ll   12
#define Vv   50257
#define Mrows (Bsz * Tlen)

typedef __attribute__((ext_vector_type(8))) short short8;
typedef __attribute__((ext_vector_type(4))) float f32x4;

__device__ __forceinline__ float bf2f(unsigned short u) {
  union { unsigned int i; float f; } v; v.i = ((unsigned int)u) << 16; return v.f;
}
__device__ __forceinline__ unsigned short f2bf(float f) {
  union { float f; unsigned int i; } v; v.f = f;
  unsigned int u = v.i;
  return (unsigned short)((u + 0x7FFFu + ((u >> 16) & 1u)) >> 16);  // RNE
}
__device__ __forceinline__ float gelu_f(float x) {
  const float c = 0.7978845608028654f; // sqrt(2/pi)
  return 0.5f * x * (1.0f + tanhf(c * (x + 0.044715f * x * x * x)));
}

// async global->LDS, 16B per lane. LDS dest must be wave-uniform base; HW adds lane*16.
__device__ __forceinline__ void gl_lds16(const unsigned short* g, unsigned short* l) {
  __builtin_amdgcn_global_load_lds(
      (const __attribute__((address_space(1))) unsigned int*)g,
      (__attribute__((address_space(3))) unsigned int*)l, 16, 0, 0);
}

// ---------------- embedding: x = wte[idx] + wpe[t] (fp32, float4) ----------------
__global__ void embed_kernel(const int* __restrict__ idx, const float* __restrict__ wte,
                             const float* __restrict__ wpe, float* __restrict__ x) {
  int i = (blockIdx.x * 256 + threadIdx.x) * 4;
  int d = i % Dm;
  int bt = i / Dm;
  int t = bt % Tlen;
  int tok = idx[bt];
  float4 a = *(const float4*)(wte + (size_t)tok * Dm + d);
  float4 p = *(const float4*)(wpe + (size_t)t * Dm + d);
  float4 r; r.x = a.x + p.x; r.y = a.y + p.y; r.z = a.z + p.z; r.w = a.w + p.w;
  *(float4*)(x + i) = r;
}

// ---------------- layernorm fp32 in -> bf16 out ----------------
__global__ __launch_bounds__(256) void ln_kernel(const float* __restrict__ x,
                                                 const float* __restrict__ w,
                                                 const float* __restrict__ b,
                                                 unsigned short* __restrict__ out) {
  __shared__ float sm[4], sm2[4];
  __shared__ float sMu, sRstd;
  int row = blockIdx.x;
  const float* xr = x + (size_t)row * Dm;
  float s = 0.f, s2 = 0.f;
  for (int i = threadIdx.x; i < Dm; i += 256) {
    float v = xr[i];
    s += v; s2 += v * v;
  }
  for (int o = 32; o > 0; o >>= 1) {
    s  += __shfl_down(s, o, 64);
    s2 += __shfl_down(s2, o, 64);
  }
  int lane = threadIdx.x & 63, wid = threadIdx.x >> 6;
  if (lane == 0) { sm[wid] = s; sm2[wid] = s2; }
  __syncthreads();
  if (threadIdx.x == 0) {
    float ts = sm[0] + sm[1] + sm[2] + sm[3];
    float ts2 = sm2[0] + sm2[1] + sm2[2] + sm2[3];
    float mu = ts / (float)Dm;
    float var = ts2 / (float)Dm - mu * mu;
    sMu = mu; sRstd = rsqrtf(var + 1e-5f);
  }
  __syncthreads();
  float mu = sMu, rstd = sRstd;
  unsigned short* yr = out + (size_t)row * Dm;
  for (int i = threadIdx.x; i < Dm; i += 256) {
    yr[i] = f2bf((xr[i] - mu) * rstd * w[i] + b[i]);
  }
}

// ---------------- transpose-convert: W[K][ldw] fp32 -> WT[n][K] bf16 ----------------
__global__ __launch_bounds__(256) void tconv_kernel(const float* __restrict__ W, int ldw,
                                                    int nValid, unsigned short* __restrict__ WT,
                                                    int K) {
  __shared__ float S[32][33];
  int n0 = blockIdx.x * 32, k0 = blockIdx.y * 32;
  int t = threadIdx.x;
  int nc = t & 31, kr0 = t >> 5;
#pragma unroll
  for (int i = 0; i < 4; ++i) {
    int kr = kr0 + i * 8;
    S[kr][nc] = (n0 + nc < nValid) ? W[(size_t)(k0 + kr) * ldw + n0 + nc] : 0.f;
  }
  __syncthreads();
  int r = t >> 3, c4 = (t & 7) * 4;
  ushort4 o;
  o.x = f2bf(S[c4 + 0][r]); o.y = f2bf(S[c4 + 1][r]);
  o.z = f2bf(S[c4 + 2][r]); o.w = f2bf(S[c4 + 3][r]);
  *(ushort4*)(WT + (size_t)(n0 + r) * K + k0 + c4) = o;
}

// ---------------- bf16 MFMA GEMM (m97 structure): C = act(A*B^T + bias) + res ----------------
__global__ __launch_bounds__(256) void gemm_bf16(
    const unsigned short* __restrict__ A, const unsigned short* __restrict__ B, int K,
    const float* __restrict__ bias, const float* __restrict__ res,
    float* __restrict__ outF, unsigned short* __restrict__ outB,
    int ldc, int nValid, int act) {
  __shared__ alignas(16) unsigned short As[128][32];
  __shared__ alignas(16) unsigned short Bs[128][32];
  int tid = threadIdx.x;
  int rowBase = blockIdx.y * 128;
  int colBase = blockIdx.x * 128;
  int w = tid >> 6, l = tid & 63;
  int wr = w >> 1, wc = w & 1;

  int srow = tid >> 2;
  int skk = (tid & 3) * 8;
  const unsigned short* aSrc = A + (size_t)(rowBase + srow) * K + skk;
  const unsigned short* bSrc = B + (size_t)(colBase + srow) * K + skk;
  unsigned short* aL0 = &As[w * 16][0];
  unsigned short* aL1 = &As[w * 16 + 64][0];
  unsigned short* bL0 = &Bs[w * 16][0];
  unsigned short* bL1 = &Bs[w * 16 + 64][0];

  f32x4 acc[4][4];
#pragma unroll
  for (int m = 0; m < 4; ++m)
#pragma unroll
    for (int n = 0; n < 4; ++n) acc[m][n] = (f32x4){0.f, 0.f, 0.f, 0.f};

  int fr = l & 15, fq = l >> 4;

  for (int k0 = 0; k0 < K; k0 += 32) {
    gl_lds16(aSrc + k0, aL0);
    gl_lds16(aSrc + (size_t)64 * K + k0, aL1);
    gl_lds16(bSrc + k0, bL0);
    gl_lds16(bSrc + (size_t)64 * K + k0, bL1);
    asm volatile("s_waitcnt vmcnt(0)" ::: "memory");
    __syncthreads();

    short8 af[4], bfr[4];
#pragma unroll
    for (int m = 0; m < 4; ++m)
      af[m] = *(const short8*)&As[wr * 64 + m * 16 + fr][fq * 8];
#pragma unroll
    for (int n = 0; n < 4; ++n)
      bfr[n] = *(const short8*)&Bs[wc * 64 + n * 16 + fr][fq * 8];
#pragma unroll
    for (int m = 0; m < 4; ++m)
#pragma unroll
      for (int n = 0; n < 4; ++n)
        acc[m][n] = __builtin_amdgcn_mfma_f32_16x16x32_bf16(af[m], bfr[n], acc[m][n], 0, 0, 0);
    __syncthreads();
  }

#pragma unroll
  for (int m = 0; m < 4; ++m) {
    int row = rowBase + wr * 64 + m * 16 + fq * 4;
#pragma unroll
    for (int n = 0; n < 4; ++n) {
      int col = colBase + wc * 64 + n * 16 + fr;
      if (col >= nValid) continue;
      float bv = bias ? bias[col] : 0.f;
#pragma unroll
      for (int j = 0; j < 4; ++j) {
        float v = acc[m][n][j] + bv;
        if (act) v = gelu_f(v);
        if (res) v += res[(size_t)(row + j) * ldc + col];
        if (outF) outF[(size_t)(row + j) * ldc + col] = v;
        else      outB[(size_t)(row + j) * ldc + col] = f2bf(v);
      }
    }
  }
}

// ---------------- MFMA flash attention ----------------
// Block = 256 thr (4 waves), one 64-query tile of one (b,h). Grid = B*H*(T/64)=384.
// K staged [t][d] XOR-swizzled via pre-swizzled global_load_lds source (double-buffered);
// V reg-staged, written transposed [d][t] (XOR-swizzled) to LDS; P through per-wave
// swizzled LDS to convert C/D layout -> A-frag layout.
__global__ __launch_bounds__(256) void attn_mfma(const unsigned short* __restrict__ qkv,
                                                 unsigned short* __restrict__ y) {
  int bx = blockIdx.x;
  int qt = bx & 15;                  // T/64 = 16
  int h  = (bx >> 4) % Hh;
  int b  = bx / (16 * Hh);
  int q0 = qt * 64;
  int tid = threadIdx.x;
  int w = tid >> 6, l = tid & 63;
  int g = l >> 4, fr = l & 15;

  __shared__ alignas(16) unsigned short Kl[2][4096];  // [t][d^sw] 8KB x2
  __shared__ alignas(16) unsigned short Vt[4096];     // [d][t^sw] 8KB
  __shared__ alignas(16) unsigned short Pl[4][1024];  // per-wave [q][t^sw] 2KB x4

  const size_t rs = 3 * Dm;
  const unsigned short* base = qkv + (size_t)(b * Tlen) * rs + h * HDm;

  // Q fragments in registers (A-frag: m=fr, k=g*8+j (+32 for ks=1))
  short8 qf[2];
  {
    const unsigned short* qrow = base + (size_t)(q0 + w * 16 + fr) * rs;
    qf[0] = *(const short8*)(qrow + g * 8);
    qf[1] = *(const short8*)(qrow + g * 8 + 32);
  }

  int vt_t = tid >> 2, vt_dc = tid & 3;  // V stage: row t, 16-d chunk
  uint4 v0r, v1r;

  f32x4 oAcc[4];
#pragma unroll
  for (int nd = 0; nd < 4; ++nd) oAcc[nd] = (f32x4){0.f, 0.f, 0.f, 0.f};
  float mRun[4] = {-1e30f, -1e30f, -1e30f, -1e30f};
  float lRun[4] = {0.f, 0.f, 0.f, 0.f};

  unsigned short* Pw = &Pl[w][0];
  int nkt = qt + 1;

  // prologue: issue K[0] + load V[0]
  {
#pragma unroll
    for (int i = 0; i < 2; ++i) {
      int c = i * 256 + tid;
      int t = c >> 3, cl = c & 7;
      int dch = cl ^ (t & 7);
      gl_lds16(base + (size_t)t * rs + Dm + dch * 8, &Kl[0][(i * 256 + w * 64) * 8]);
    }
    const unsigned short* p = base + (size_t)vt_t * rs + 2 * Dm + vt_dc * 16;
    v0r = *(const uint4*)p;
    v1r = *(const uint4*)(p + 8);
  }

  for (int kt = 0; kt < nkt; ++kt) {
    int cur = kt & 1;
    int kbase = kt * 64;
    asm volatile("s_waitcnt vmcnt(0)" ::: "memory");
    __builtin_amdgcn_s_barrier();           // K[kt] in LDS, V[kt] in regs, prev tile fully read

    // write V transposed into LDS: elem (t,d) -> Vt[d*64 + (t ^ ((d&7)<<3))]
    {
      union { uint4 u; unsigned short s[8]; } a, bb;
      a.u = v0r; bb.u = v1r;
#pragma unroll
      for (int j = 0; j < 8; ++j) {
        int d = vt_dc * 16 + j;
        Vt[d * 64 + (vt_t ^ ((d & 7) << 3))] = a.s[j];
        int d2 = d + 8;
        Vt[d2 * 64 + (vt_t ^ ((d2 & 7) << 3))] = bb.s[j];
      }
    }
    // prefetch next tile (stays in flight across the barrier below)
    if (kt + 1 < nkt) {
      int kb = kbase + 64;
#pragma unroll
      for (int i = 0; i < 2; ++i) {
        int c = i * 256 + tid;
        int t = c >> 3, cl = c & 7;
        int dch = cl ^ (t & 7);
        gl_lds16(base + (size_t)(kb + t) * rs + Dm + dch * 8,
                 &Kl[cur ^ 1][(i * 256 + w * 64) * 8]);
      }
      const unsigned short* p = base + (size_t)(kb + vt_t) * rs + 2 * Dm + vt_dc * 16;
      v0r = *(const uint4*)p;
      v1r = *(const uint4*)(p + 8);
    }
    asm volatile("s_waitcnt lgkmcnt(0)" ::: "memory");  // Vt writes done (per wave)
    __builtin_amdgcn_s_barrier();

    // ---- QK^T: S[16q][64t] in 4 C/D tiles ----
    f32x4 sAcc[4];
#pragma unroll
    for (int nt = 0; nt < 4; ++nt) sAcc[nt] = (f32x4){0.f, 0.f, 0.f, 0.f};
#pragma unroll
    for (int ks = 0; ks < 2; ++ks)
#pragma unroll
      for (int nt = 0; nt < 4; ++nt) {
        int kcol = nt * 16 + fr;
        short8 kf = *(const short8*)&Kl[cur][kcol * 64 + ((g * 8 + ks * 32) ^ ((kcol & 7) << 3))];
        sAcc[nt] = __builtin_amdgcn_mfma_f32_16x16x32_bf16(qf[ks], kf, sAcc[nt], 0, 0, 0);
      }

    // ---- online softmax (per q-row j; rows replicated over 16-lane groups) ----
    float corr[4];
#pragma unroll
    for (int j = 0; j < 4; ++j) {
      int qg = q0 + w * 16 + g * 4 + j;
      float tm = -1e30f;
#pragma unroll
      for (int nt = 0; nt < 4; ++nt) {
        float s = sAcc[nt][j] * 0.125f;
        int tg = kbase + nt * 16 + fr;
        if (tg > qg) s = -1e30f;
        sAcc[nt][j] = s;
        tm = fmaxf(tm, s);
      }
      tm = fmaxf(tm, __shfl_xor(tm, 1, 16));
      tm = fmaxf(tm, __shfl_xor(tm, 2, 16));
      tm = fmaxf(tm, __shfl_xor(tm, 4, 16));
      tm = fmaxf(tm, __shfl_xor(tm, 8, 16));
      float mN = fmaxf(mRun[j], tm);
      corr[j] = __expf(mRun[j] - mN);
      mRun[j] = mN;
      float ps = 0.f;
#pragma unroll
      for (int nt = 0; nt < 4; ++nt) {
        float p = __expf(sAcc[nt][j] - mN);
        sAcc[nt][j] = p;
        ps += p;
      }
      ps += __shfl_xor(ps, 1, 16);
      ps += __shfl_xor(ps, 2, 16);
      ps += __shfl_xor(ps, 4, 16);
      ps += __shfl_xor(ps, 8, 16);
      lRun[j] = lRun[j] * corr[j] + ps;
    }

    // P (C/D layout) -> per-wave LDS, bf16, swizzled
#pragma unroll
    for (int nt = 0; nt < 4; ++nt)
#pragma unroll
      for (int j = 0; j < 4; ++j) {
        int q = g * 4 + j;
        int t = nt * 16 + fr;
        Pw[q * 64 + (t ^ ((q & 7) << 3))] = f2bf(sAcc[nt][j]);
      }
    // rescale O
#pragma unroll
    for (int nd = 0; nd < 4; ++nd)
#pragma unroll
      for (int j = 0; j < 4; ++j) oAcc[nd][j] *= corr[j];

    // ---- PV: O[16q][64d] += P @ V ----
#pragma unroll
    for (int ks = 0; ks < 2; ++ks) {
      short8 pf = *(const short8*)&Pw[fr * 64 + ((g * 8 + ks * 32) ^ ((fr & 7) << 3))];
#pragma unroll
      for (int nd = 0; nd < 4; ++nd) {
        int d = nd * 16 + fr;
        short8 vf = *(const short8*)&Vt[d * 64 + ((g * 8 + ks * 32) ^ ((fr & 7) << 3))];
        oAcc[nd] = __builtin_amdgcn_mfma_f32_16x16x32_bf16(pf, vf, oAcc[nd], 0, 0, 0);
      }
    }
  }

  // epilogue
#pragma unroll
  for (int j = 0; j < 4; ++j) {
    float inv = 1.0f / lRun[j];
    int q = q0 + w * 16 + g * 4 + j;
    unsigned short* yr = y + (size_t)(b * Tlen + q) * Dm + h * HDm + fr;
#pragma unroll
    for (int nd = 0; nd < 4; ++nd)
      yr[nd * 16] = f2bf(oAcc[nd][j] * inv);
  }
}

extern "C" void kernel_launch(void* const* d_in, const int* in_sizes, int n_in,
                              void* d_out, int out_size, void* d_ws, size_t ws_size,
                              hipStream_t stream) {
  const int*   idx    = (const int*)d_in[0];
  const float* wte    = (const float*)d_in[1];
  const float* wpe    = (const float*)d_in[2];
  const float* ln1_w  = (const float*)d_in[3];
  const float* ln1_b  = (const float*)d_in[4];
  const float* attn_w = (const float*)d_in[5];
  const float* attn_b = (const float*)d_in[6];
  const float* proj_w = (const float*)d_in[7];
  const float* proj_b = (const float*)d_in[8];
  const float* ln2_w  = (const float*)d_in[9];
  const float* ln2_b  = (const float*)d_in[10];
  const float* fc_w   = (const float*)d_in[11];
  const float* fc_b   = (const float*)d_in[12];
  const float* fc2_w  = (const float*)d_in[13];
  const float* fc2_b  = (const float*)d_in[14];
  const float* lnf_w  = (const float*)d_in[15];
  const float* lnf_b  = (const float*)d_in[16];
  const float* lmw    = (const float*)d_in[17];
  float* out = (float*)d_out;

  float* x = (float*)d_ws;                                    // [M][768] fp32
  unsigned short* qkvb = (unsigned short*)(x + (size_t)Mrows * Dm);   // [M][2304] bf16
  unsigned short* xb   = qkvb + (size_t)Mrows * 3 * Dm;       // [M][768] bf16
  unsigned short* yb   = xb + (size_t)Mrows * Dm;             // [M][768] bf16
  unsigned short* mb   = yb + (size_t)Mrows * Dm;             // [M][3072] bf16
  unsigned short* wbuf = mb + (size_t)Mrows * 4 * Dm;         // per-layer W^T bf16
  unsigned short* wAttn = wbuf;                               // [2304][768]
  unsigned short* wProj = wAttn + (size_t)3 * Dm * Dm;        // [768][768]
  unsigned short* wFc   = wProj + (size_t)Dm * Dm;            // [3072][768]
  unsigned short* wFc2  = wFc + (size_t)4 * Dm * Dm;          // [768][3072]

  embed_kernel<<<(Mrows * Dm) / 1024, 256, 0, stream>>>(idx, wte, wpe, x);

  for (int l = 0; l < Ll; ++l) {
    tconv_kernel<<<dim3(72, 24), 256, 0, stream>>>(attn_w + (size_t)l * Dm * 3 * Dm, 3 * Dm, 3 * Dm, wAttn, Dm);
    tconv_kernel<<<dim3(24, 24), 256, 0, stream>>>(proj_w + (size_t)l * Dm * Dm, Dm, Dm, wProj, Dm);
    tconv_kernel<<<dim3(96, 24), 256, 0, stream>>>(fc_w + (size_t)l * Dm * 4 * Dm, 4 * Dm, 4 * Dm, wFc, Dm);
    tconv_kernel<<<dim3(24, 96), 256, 0, stream>>>(fc2_w + (size_t)l * 4 * Dm * Dm, Dm, Dm, wFc2, 4 * Dm);

    ln_kernel<<<Mrows, 256, 0, stream>>>(x, ln1_w + l * Dm, ln1_b + l * Dm, xb);
    gemm_bf16<<<dim3(18, 16), 256, 0, stream>>>(xb, wAttn, Dm, attn_b + (size_t)l * 3 * Dm,
                                                nullptr, nullptr, qkvb, 3 * Dm, 3 * Dm, 0);
    attn_mfma<<<Bsz * Hh * 16, 256, 0, stream>>>(qkvb, yb);
    gemm_bf16<<<dim3(6, 16), 256, 0, stream>>>(yb, wProj, Dm, proj_b + (size_t)l * Dm,
                                               x, x, nullptr, Dm, Dm, 0);
    ln_kernel<<<Mrows, 256, 0, stream>>>(x, ln2_w + l * Dm, ln2_b + l * Dm, xb);
    gemm_bf16<<<dim3(24, 16), 256, 0, stream>>>(xb, wFc, Dm, fc_b + (size_t)l * 4 * Dm,
                                                nullptr, nullptr, mb, 4 * Dm, 4 * Dm, 1);
    gemm_bf16<<<dim3(6, 16), 256, 0, stream>>>(mb, wFc2, 4 * Dm, fc2_b + (size_t)l * Dm,
                                               x, x, nullptr, Dm, Dm, 0);
  }

  ln_kernel<<<Mrows, 256, 0, stream>>>(x, lnf_w, lnf_b, xb);
  for (int base = 0; base < Vv; base += 8192) {
    int ncv = Vv - base; if (ncv > 8192) ncv = 8192;
    int ntiles = (ncv + 127) / 128;
    tconv_kernel<<<dim3(ntiles * 4, 24), 256, 0, stream>>>(lmw + base, Vv, ncv, wbuf, Dm);
    gemm_bf16<<<dim3(ntiles, 16), 256, 0, stream>>>(xb, wbuf, Dm, nullptr, nullptr,
                                                    out + base, nullptr, Vv, ncv, 0);
  }
}

// Round 4
// 2666.888 us; speedup vs baseline: 7.8740x; 1.3660x over previous
//
#include <hip/hip_runtime.h>
#include <math.h>

// GPT-2 small forward: B=2, T=1024, D=768, H=12, HD=64, L=12, V=50257
#define Bsz  2
#define Tlen 1024
#define Dm   768
#define Hh   12
#define HDm  64
#define Ll   12
#define Vv   50257
#define Mrows (Bsz * Tlen)

typedef __attribute__((ext_vector_type(8))) short short8;
typedef __attribute__((ext_vector_type(4))) float f32x4;

__device__ __forceinline__ float bf2f(unsigned short u) {
  union { unsigned int i; float f; } v; v.i = ((unsigned int)u) << 16; return v.f;
}
__device__ __forceinline__ unsigned short f2bf(float f) {
  union { float f; unsigned int i; } v; v.f = f;
  unsigned int u = v.i;
  return (unsigned short)((u + 0x7FFFu + ((u >> 16) & 1u)) >> 16);  // RNE
}
__device__ __forceinline__ float gelu_f(float x) {
  const float c = 0.7978845608028654f; // sqrt(2/pi)
  return 0.5f * x * (1.0f + tanhf(c * (x + 0.044715f * x * x * x)));
}

// async global->LDS, 16B per lane. LDS dest must be wave-uniform base; HW adds lane*16.
__device__ __forceinline__ void gl_lds16(const unsigned short* g, unsigned short* l) {
  __builtin_amdgcn_global_load_lds(
      (const __attribute__((address_space(1))) unsigned int*)g,
      (__attribute__((address_space(3))) unsigned int*)l, 16, 0, 0);
}

// ---------------- embedding ----------------
__global__ void embed_kernel(const int* __restrict__ idx, const float* __restrict__ wte,
                             const float* __restrict__ wpe, float* __restrict__ x) {
  int i = (blockIdx.x * 256 + threadIdx.x) * 4;
  int d = i % Dm;
  int bt = i / Dm;
  int t = bt % Tlen;
  int tok = idx[bt];
  float4 a = *(const float4*)(wte + (size_t)tok * Dm + d);
  float4 p = *(const float4*)(wpe + (size_t)t * Dm + d);
  float4 r; r.x = a.x + p.x; r.y = a.y + p.y; r.z = a.z + p.z; r.w = a.w + p.w;
  *(float4*)(x + i) = r;
}

// ---------------- layernorm: wave-per-row, 4 rows/block ----------------
__global__ __launch_bounds__(256) void ln_wave(const float* __restrict__ x,
                                               const float* __restrict__ w,
                                               const float* __restrict__ b,
                                               unsigned short* __restrict__ out) {
  int tid = threadIdx.x, wv = tid >> 6, l = tid & 63;
  int row = blockIdx.x * 4 + wv;
  const float* xr = x + (size_t)row * Dm;
  float4 v[3];
  float s = 0.f, s2 = 0.f;
#pragma unroll
  for (int i = 0; i < 3; ++i) {
    v[i] = *(const float4*)(xr + l * 4 + i * 256);
    s += v[i].x + v[i].y + v[i].z + v[i].w;
    s2 += v[i].x * v[i].x + v[i].y * v[i].y + v[i].z * v[i].z + v[i].w * v[i].w;
  }
#pragma unroll
  for (int o = 1; o < 64; o <<= 1) {
    s += __shfl_xor(s, o, 64);
    s2 += __shfl_xor(s2, o, 64);
  }
  float mu = s * (1.0f / Dm);
  float var = s2 * (1.0f / Dm) - mu * mu;
  float rstd = rsqrtf(var + 1e-5f);
  unsigned short* yr = out + (size_t)row * Dm;
#pragma unroll
  for (int i = 0; i < 3; ++i) {
    float4 wv4 = *(const float4*)(w + l * 4 + i * 256);
    float4 bv4 = *(const float4*)(b + l * 4 + i * 256);
    ushort4 o4;
    o4.x = f2bf((v[i].x - mu) * rstd * wv4.x + bv4.x);
    o4.y = f2bf((v[i].y - mu) * rstd * wv4.y + bv4.y);
    o4.z = f2bf((v[i].z - mu) * rstd * wv4.z + bv4.z);
    o4.w = f2bf((v[i].w - mu) * rstd * wv4.w + bv4.w);
    *(ushort4*)(yr + l * 4 + i * 256) = o4;
  }
}

// ---------------- generic transpose-convert (lm_head chunks) ----------------
__global__ __launch_bounds__(256) void tconv_kernel(const float* __restrict__ W, int ldw,
                                                    int nValid, unsigned short* __restrict__ WT,
                                                    int K) {
  __shared__ float S[32][33];
  int n0 = blockIdx.x * 32, k0 = blockIdx.y * 32;
  int t = threadIdx.x;
  int nc = t & 31, kr0 = t >> 5;
#pragma unroll
  for (int i = 0; i < 4; ++i) {
    int kr = kr0 + i * 8;
    S[kr][nc] = (n0 + nc < nValid) ? W[(size_t)(k0 + kr) * ldw + n0 + nc] : 0.f;
  }
  __syncthreads();
  int r = t >> 3, c4 = (t & 7) * 4;
  ushort4 o;
  o.x = f2bf(S[c4 + 0][r]); o.y = f2bf(S[c4 + 1][r]);
  o.z = f2bf(S[c4 + 2][r]); o.w = f2bf(S[c4 + 3][r]);
  *(ushort4*)(WT + (size_t)(n0 + r) * K + k0 + c4) = o;
}

// ---------------- batched per-layer transpose-convert: 4 weight mats, 1 dispatch ----------------
// seg 0: attn [768][2304] -> [2304][768]  tiles 72x24 = 1728
// seg 1: proj [768][768]  -> [768][768]   tiles 24x24 = 576   (cum 2304)
// seg 2: fc   [768][3072] -> [3072][768]  tiles 96x24 = 2304  (cum 4608)
// seg 3: fc2  [3072][768] -> [768][3072]  tiles 24x96 = 2304  (cum 6912)
__global__ __launch_bounds__(256) void tconv4_kernel(
    const float* __restrict__ wA, const float* __restrict__ wP,
    const float* __restrict__ wF, const float* __restrict__ wF2,
    unsigned short* __restrict__ oA, unsigned short* __restrict__ oP,
    unsigned short* __restrict__ oF, unsigned short* __restrict__ oF2) {
  int bid = blockIdx.x;
  const float* W; unsigned short* WT; int ldw, K, ntn, local;
  if (bid < 1728)      { W = wA;  WT = oA;  ldw = 2304; K = 768;  ntn = 72; local = bid; }
  else if (bid < 2304) { W = wP;  WT = oP;  ldw = 768;  K = 768;  ntn = 24; local = bid - 1728; }
  else if (bid < 4608) { W = wF;  WT = oF;  ldw = 3072; K = 768;  ntn = 96; local = bid - 2304; }
  else                 { W = wF2; WT = oF2; ldw = 768;  K = 3072; ntn = 24; local = bid - 4608; }
  int n0 = (local % ntn) * 32, k0 = (local / ntn) * 32;
  __shared__ float S[32][33];
  int t = threadIdx.x;
  int nc = t & 31, kr0 = t >> 5;
#pragma unroll
  for (int i = 0; i < 4; ++i) {
    int kr = kr0 + i * 8;
    S[kr][nc] = W[(size_t)(k0 + kr) * ldw + n0 + nc];
  }
  __syncthreads();
  int r = t >> 3, c4 = (t & 7) * 4;
  ushort4 o;
  o.x = f2bf(S[c4 + 0][r]); o.y = f2bf(S[c4 + 1][r]);
  o.z = f2bf(S[c4 + 2][r]); o.w = f2bf(S[c4 + 3][r]);
  *(ushort4*)(WT + (size_t)(n0 + r) * K + k0 + c4) = o;
}

// ---------------- bf16 MFMA GEMM, 128x128 tile (lm_head) ----------------
__global__ __launch_bounds__(256) void gemm_bf16(
    const unsigned short* __restrict__ A, const unsigned short* __restrict__ B, int K,
    const float* __restrict__ bias, const float* __restrict__ res,
    float* __restrict__ outF, unsigned short* __restrict__ outB,
    int ldc, int nValid, int act) {
  __shared__ alignas(16) unsigned short As[128][32];
  __shared__ alignas(16) unsigned short Bs[128][32];
  int tid = threadIdx.x;
  int rowBase = blockIdx.y * 128;
  int colBase = blockIdx.x * 128;
  int w = tid >> 6, l = tid & 63;
  int wr = w >> 1, wc = w & 1;

  int srow = tid >> 2;
  int skk = (tid & 3) * 8;
  const unsigned short* aSrc = A + (size_t)(rowBase + srow) * K + skk;
  const unsigned short* bSrc = B + (size_t)(colBase + srow) * K + skk;
  unsigned short* aL0 = &As[w * 16][0];
  unsigned short* aL1 = &As[w * 16 + 64][0];
  unsigned short* bL0 = &Bs[w * 16][0];
  unsigned short* bL1 = &Bs[w * 16 + 64][0];

  f32x4 acc[4][4];
#pragma unroll
  for (int m = 0; m < 4; ++m)
#pragma unroll
    for (int n = 0; n < 4; ++n) acc[m][n] = (f32x4){0.f, 0.f, 0.f, 0.f};

  int fr = l & 15, fq = l >> 4;

  for (int k0 = 0; k0 < K; k0 += 32) {
    gl_lds16(aSrc + k0, aL0);
    gl_lds16(aSrc + (size_t)64 * K + k0, aL1);
    gl_lds16(bSrc + k0, bL0);
    gl_lds16(bSrc + (size_t)64 * K + k0, bL1);
    asm volatile("s_waitcnt vmcnt(0)" ::: "memory");
    __syncthreads();

    short8 af[4], bfr[4];
#pragma unroll
    for (int m = 0; m < 4; ++m)
      af[m] = *(const short8*)&As[wr * 64 + m * 16 + fr][fq * 8];
#pragma unroll
    for (int n = 0; n < 4; ++n)
      bfr[n] = *(const short8*)&Bs[wc * 64 + n * 16 + fr][fq * 8];
#pragma unroll
    for (int m = 0; m < 4; ++m)
#pragma unroll
      for (int n = 0; n < 4; ++n)
        acc[m][n] = __builtin_amdgcn_mfma_f32_16x16x32_bf16(af[m], bfr[n], acc[m][n], 0, 0, 0);
    __syncthreads();
  }

#pragma unroll
  for (int m = 0; m < 4; ++m) {
    int row = rowBase + wr * 64 + m * 16 + fq * 4;
#pragma unroll
    for (int n = 0; n < 4; ++n) {
      int col = colBase + wc * 64 + n * 16 + fr;
      if (col >= nValid) continue;
      float bv = bias ? bias[col] : 0.f;
#pragma unroll
      for (int j = 0; j < 4; ++j) {
        float v = acc[m][n][j] + bv;
        if (act) v = gelu_f(v);
        if (res) v += res[(size_t)(row + j) * ldc + col];
        if (outF) outF[(size_t)(row + j) * ldc + col] = v;
        else      outB[(size_t)(row + j) * ldc + col] = f2bf(v);
      }
    }
  }
}

// ---------------- bf16 MFMA GEMM, 64x128 tile (trunk: small grids -> high occupancy) ----------------
// 12KB LDS, 4 waves: wave w owns cols [w*32, w*32+32). acc[4][2]. No N tail (N%128==0).
__global__ __launch_bounds__(256) void gemm_bf16_sm(
    const unsigned short* __restrict__ A, const unsigned short* __restrict__ B, int K,
    const float* __restrict__ bias, const float* __restrict__ res,
    float* __restrict__ outF, unsigned short* __restrict__ outB,
    int ldc, int act) {
  __shared__ alignas(16) unsigned short As[64][32];
  __shared__ alignas(16) unsigned short Bs[128][32];
  int tid = threadIdx.x;
  int rowBase = blockIdx.y * 64;
  int colBase = blockIdx.x * 128;
  int w = tid >> 6, l = tid & 63;
  int fr = l & 15, fq = l >> 4;

  // staging: each gl_lds16 issue covers 16 rows (64B/row); lane -> row l>>2, chunk (l&3)*8
  int srow = l >> 2, skk = (l & 3) * 8;
  const unsigned short* aSrc = A + (size_t)(rowBase + w * 16 + srow) * K + skk;
  const unsigned short* bSrc = B + (size_t)(colBase + w * 16 + srow) * K + skk;
  unsigned short* aL = &As[w * 16][0];
  unsigned short* bL0 = &Bs[w * 16][0];
  unsigned short* bL1 = &Bs[w * 16 + 64][0];

  f32x4 acc[4][2];
#pragma unroll
  for (int m = 0; m < 4; ++m)
#pragma unroll
    for (int n = 0; n < 2; ++n) acc[m][n] = (f32x4){0.f, 0.f, 0.f, 0.f};

  for (int k0 = 0; k0 < K; k0 += 32) {
    gl_lds16(aSrc + k0, aL);
    gl_lds16(bSrc + k0, bL0);
    gl_lds16(bSrc + (size_t)64 * K + k0, bL1);
    asm volatile("s_waitcnt vmcnt(0)" ::: "memory");
    __syncthreads();

    short8 af[4], bfr[2];
#pragma unroll
    for (int m = 0; m < 4; ++m)
      af[m] = *(const short8*)&As[m * 16 + fr][fq * 8];
#pragma unroll
    for (int n = 0; n < 2; ++n)
      bfr[n] = *(const short8*)&Bs[w * 32 + n * 16 + fr][fq * 8];
#pragma unroll
    for (int m = 0; m < 4; ++m)
#pragma unroll
      for (int n = 0; n < 2; ++n)
        acc[m][n] = __builtin_amdgcn_mfma_f32_16x16x32_bf16(af[m], bfr[n], acc[m][n], 0, 0, 0);
    __syncthreads();
  }

#pragma unroll
  for (int m = 0; m < 4; ++m) {
    int row = rowBase + m * 16 + fq * 4;
#pragma unroll
    for (int n = 0; n < 2; ++n) {
      int col = colBase + w * 32 + n * 16 + fr;
      float bv = bias ? bias[col] : 0.f;
#pragma unroll
      for (int j = 0; j < 4; ++j) {
        float v = acc[m][n][j] + bv;
        if (act) v = gelu_f(v);
        if (res) v += res[(size_t)(row + j) * ldc + col];
        if (outF) outF[(size_t)(row + j) * ldc + col] = v;
        else      outB[(size_t)(row + j) * ldc + col] = f2bf(v);
      }
    }
  }
}

// ---------------- MFMA flash attention (unchanged from round 3) ----------------
__global__ __launch_bounds__(256) void attn_mfma(const unsigned short* __restrict__ qkv,
                                                 unsigned short* __restrict__ y) {
  int bx = blockIdx.x;
  int qt = bx & 15;                  // T/64 = 16
  int h  = (bx >> 4) % Hh;
  int b  = bx / (16 * Hh);
  int q0 = qt * 64;
  int tid = threadIdx.x;
  int w = tid >> 6, l = tid & 63;
  int g = l >> 4, fr = l & 15;

  __shared__ alignas(16) unsigned short Kl[2][4096];
  __shared__ alignas(16) unsigned short Vt[4096];
  __shared__ alignas(16) unsigned short Pl[4][1024];

  const size_t rs = 3 * Dm;
  const unsigned short* base = qkv + (size_t)(b * Tlen) * rs + h * HDm;

  short8 qf[2];
  {
    const unsigned short* qrow = base + (size_t)(q0 + w * 16 + fr) * rs;
    qf[0] = *(const short8*)(qrow + g * 8);
    qf[1] = *(const short8*)(qrow + g * 8 + 32);
  }

  int vt_t = tid >> 2, vt_dc = tid & 3;
  uint4 v0r, v1r;

  f32x4 oAcc[4];
#pragma unroll
  for (int nd = 0; nd < 4; ++nd) oAcc[nd] = (f32x4){0.f, 0.f, 0.f, 0.f};
  float mRun[4] = {-1e30f, -1e30f, -1e30f, -1e30f};
  float lRun[4] = {0.f, 0.f, 0.f, 0.f};

  unsigned short* Pw = &Pl[w][0];
  int nkt = qt + 1;

  {
#pragma unroll
    for (int i = 0; i < 2; ++i) {
      int c = i * 256 + tid;
      int t = c >> 3, cl = c & 7;
      int dch = cl ^ (t & 7);
      gl_lds16(base + (size_t)t * rs + Dm + dch * 8, &Kl[0][(i * 256 + w * 64) * 8]);
    }
    const unsigned short* p = base + (size_t)vt_t * rs + 2 * Dm + vt_dc * 16;
    v0r = *(const uint4*)p;
    v1r = *(const uint4*)(p + 8);
  }

  for (int kt = 0; kt < nkt; ++kt) {
    int cur = kt & 1;
    int kbase = kt * 64;
    asm volatile("s_waitcnt vmcnt(0)" ::: "memory");
    __builtin_amdgcn_s_barrier();

    {
      union { uint4 u; unsigned short s[8]; } a, bb;
      a.u = v0r; bb.u = v1r;
#pragma unroll
      for (int j = 0; j < 8; ++j) {
        int d = vt_dc * 16 + j;
        Vt[d * 64 + (vt_t ^ ((d & 7) << 3))] = a.s[j];
        int d2 = d + 8;
        Vt[d2 * 64 + (vt_t ^ ((d2 & 7) << 3))] = bb.s[j];
      }
    }
    if (kt + 1 < nkt) {
      int kb = kbase + 64;
#pragma unroll
      for (int i = 0; i < 2; ++i) {
        int c = i * 256 + tid;
        int t = c >> 3, cl = c & 7;
        int dch = cl ^ (t & 7);
        gl_lds16(base + (size_t)(kb + t) * rs + Dm + dch * 8,
                 &Kl[cur ^ 1][(i * 256 + w * 64) * 8]);
      }
      const unsigned short* p = base + (size_t)(kb + vt_t) * rs + 2 * Dm + vt_dc * 16;
      v0r = *(const uint4*)p;
      v1r = *(const uint4*)(p + 8);
    }
    asm volatile("s_waitcnt lgkmcnt(0)" ::: "memory");
    __builtin_amdgcn_s_barrier();

    f32x4 sAcc[4];
#pragma unroll
    for (int nt = 0; nt < 4; ++nt) sAcc[nt] = (f32x4){0.f, 0.f, 0.f, 0.f};
#pragma unroll
    for (int ks = 0; ks < 2; ++ks)
#pragma unroll
      for (int nt = 0; nt < 4; ++nt) {
        int kcol = nt * 16 + fr;
        short8 kf = *(const short8*)&Kl[cur][kcol * 64 + ((g * 8 + ks * 32) ^ ((kcol & 7) << 3))];
        sAcc[nt] = __builtin_amdgcn_mfma_f32_16x16x32_bf16(qf[ks], kf, sAcc[nt], 0, 0, 0);
      }

    float corr[4];
#pragma unroll
    for (int j = 0; j < 4; ++j) {
      int qg = q0 + w * 16 + g * 4 + j;
      float tm = -1e30f;
#pragma unroll
      for (int nt = 0; nt < 4; ++nt) {
        float s = sAcc[nt][j] * 0.125f;
        int tg = kbase + nt * 16 + fr;
        if (tg > qg) s = -1e30f;
        sAcc[nt][j] = s;
        tm = fmaxf(tm, s);
      }
      tm = fmaxf(tm, __shfl_xor(tm, 1, 16));
      tm = fmaxf(tm, __shfl_xor(tm, 2, 16));
      tm = fmaxf(tm, __shfl_xor(tm, 4, 16));
      tm = fmaxf(tm, __shfl_xor(tm, 8, 16));
      float mN = fmaxf(mRun[j], tm);
      corr[j] = __expf(mRun[j] - mN);
      mRun[j] = mN;
      float ps = 0.f;
#pragma unroll
      for (int nt = 0; nt < 4; ++nt) {
        float p = __expf(sAcc[nt][j] - mN);
        sAcc[nt][j] = p;
        ps += p;
      }
      ps += __shfl_xor(ps, 1, 16);
      ps += __shfl_xor(ps, 2, 16);
      ps += __shfl_xor(ps, 4, 16);
      ps += __shfl_xor(ps, 8, 16);
      lRun[j] = lRun[j] * corr[j] + ps;
    }

#pragma unroll
    for (int nt = 0; nt < 4; ++nt)
#pragma unroll
      for (int j = 0; j < 4; ++j) {
        int q = g * 4 + j;
        int t = nt * 16 + fr;
        Pw[q * 64 + (t ^ ((q & 7) << 3))] = f2bf(sAcc[nt][j]);
      }
#pragma unroll
    for (int nd = 0; nd < 4; ++nd)
#pragma unroll
      for (int j = 0; j < 4; ++j) oAcc[nd][j] *= corr[j];

#pragma unroll
    for (int ks = 0; ks < 2; ++ks) {
      short8 pf = *(const short8*)&Pw[fr * 64 + ((g * 8 + ks * 32) ^ ((fr & 7) << 3))];
#pragma unroll
      for (int nd = 0; nd < 4; ++nd) {
        int d = nd * 16 + fr;
        short8 vf = *(const short8*)&Vt[d * 64 + ((g * 8 + ks * 32) ^ ((fr & 7) << 3))];
        oAcc[nd] = __builtin_amdgcn_mfma_f32_16x16x32_bf16(pf, vf, oAcc[nd], 0, 0, 0);
      }
    }
  }

#pragma unroll
  for (int j = 0; j < 4; ++j) {
    float inv = 1.0f / lRun[j];
    int q = q0 + w * 16 + g * 4 + j;
    unsigned short* yr = y + (size_t)(b * Tlen + q) * Dm + h * HDm + fr;
#pragma unroll
    for (int nd = 0; nd < 4; ++nd)
      yr[nd * 16] = f2bf(oAcc[nd][j] * inv);
  }
}

extern "C" void kernel_launch(void* const* d_in, const int* in_sizes, int n_in,
                              void* d_out, int out_size, void* d_ws, size_t ws_size,
                              hipStream_t stream) {
  const int*   idx    = (const int*)d_in[0];
  const float* wte    = (const float*)d_in[1];
  const float* wpe    = (const float*)d_in[2];
  const float* ln1_w  = (const float*)d_in[3];
  const float* ln1_b  = (const float*)d_in[4];
  const float* attn_w = (const float*)d_in[5];
  const float* attn_b = (const float*)d_in[6];
  const float* proj_w = (const float*)d_in[7];
  const float* proj_b = (const float*)d_in[8];
  const float* ln2_w  = (const float*)d_in[9];
  const float* ln2_b  = (const float*)d_in[10];
  const float* fc_w   = (const float*)d_in[11];
  const float* fc_b   = (const float*)d_in[12];
  const float* fc2_w  = (const float*)d_in[13];
  const float* fc2_b  = (const float*)d_in[14];
  const float* lnf_w  = (const float*)d_in[15];
  const float* lnf_b  = (const float*)d_in[16];
  const float* lmw    = (const float*)d_in[17];
  float* out = (float*)d_out;

  float* x = (float*)d_ws;                                    // [M][768] fp32
  unsigned short* qkvb = (unsigned short*)(x + (size_t)Mrows * Dm);   // [M][2304] bf16
  unsigned short* xb   = qkvb + (size_t)Mrows * 3 * Dm;       // [M][768] bf16
  unsigned short* yb   = xb + (size_t)Mrows * Dm;             // [M][768] bf16
  unsigned short* mb   = yb + (size_t)Mrows * Dm;             // [M][3072] bf16
  unsigned short* wbuf = mb + (size_t)Mrows * 4 * Dm;         // weights region
  unsigned short* wAttn = wbuf;                               // [2304][768]
  unsigned short* wProj = wAttn + (size_t)3 * Dm * Dm;        // [768][768]
  unsigned short* wFc   = wProj + (size_t)Dm * Dm;            // [3072][768]
  unsigned short* wFc2  = wFc + (size_t)4 * Dm * Dm;          // [768][3072]

  // lm_head chunk size from available workspace (ws_size >= 56.6MB proven)
  const size_t baseBytes = (size_t)Mrows * Dm * 4 + (size_t)Mrows * 9 * Dm * 2;  // 34.6MB
  size_t availShorts = (ws_size - baseBytes) / 2;
  long long cc = (long long)(availShorts / Dm) & ~127LL;
  if (cc > 50304) cc = 50304;
  const int chunkCols = (int)cc;

  embed_kernel<<<(Mrows * Dm) / 1024, 256, 0, stream>>>(idx, wte, wpe, x);

  for (int l = 0; l < Ll; ++l) {
    tconv4_kernel<<<6912, 256, 0, stream>>>(
        attn_w + (size_t)l * Dm * 3 * Dm, proj_w + (size_t)l * Dm * Dm,
        fc_w + (size_t)l * Dm * 4 * Dm, fc2_w + (size_t)l * 4 * Dm * Dm,
        wAttn, wProj, wFc, wFc2);

    ln_wave<<<Mrows / 4, 256, 0, stream>>>(x, ln1_w + l * Dm, ln1_b + l * Dm, xb);
    gemm_bf16_sm<<<dim3(18, 32), 256, 0, stream>>>(xb, wAttn, Dm, attn_b + (size_t)l * 3 * Dm,
                                                   nullptr, nullptr, qkvb, 3 * Dm, 0);
    attn_mfma<<<Bsz * Hh * 16, 256, 0, stream>>>(qkvb, yb);
    gemm_bf16_sm<<<dim3(6, 32), 256, 0, stream>>>(yb, wProj, Dm, proj_b + (size_t)l * Dm,
                                                  x, x, nullptr, Dm, 0);
    ln_wave<<<Mrows / 4, 256, 0, stream>>>(x, ln2_w + l * Dm, ln2_b + l * Dm, xb);
    gemm_bf16_sm<<<dim3(24, 32), 256, 0, stream>>>(xb, wFc, Dm, fc_b + (size_t)l * 4 * Dm,
                                                   nullptr, nullptr, mb, 4 * Dm, 1);
    gemm_bf16_sm<<<dim3(6, 32), 256, 0, stream>>>(mb, wFc2, 4 * Dm, fc2_b + (size_t)l * Dm,
                                                  x, x, nullptr, Dm, 0);
  }

  ln_wave<<<Mrows / 4, 256, 0, stream>>>(x, lnf_w, lnf_b, xb);
  for (int base = 0; base < Vv; base += chunkCols) {
    int ncv = Vv - base; if (ncv > chunkCols) ncv = chunkCols;
    int ntiles = (ncv + 127) / 128;
    tconv_kernel<<<dim3((ncv + 31) / 32, 24), 256, 0, stream>>>(lmw + base, Vv, ncv, wbuf, Dm);
    gemm_bf16<<<dim3(ntiles, 16), 256, 0, stream>>>(xb, wbuf, Dm, nullptr, nullptr,
                                                    out + base, nullptr, Vv, ncv, 0);
  }
}